// Round 1
// baseline (254.792 us; speedup 1.0000x reference)
//
#include <hip/hip_runtime.h>
#include <cstddef>

// Depthwise 7x7 conv, stride 1, pad 3, with 4-fold rotational kernel symmetrization.
// x: [N=16, C=384, 64, 64] fp32, w: [384,1,7,7] fp32, out: [16,384,64,64] fp32.
//
// One block per (n,c) 64x64 plane. Stage padded 70x70 plane in LDS (row stride 72),
// symmetrize weights per-channel into LDS then registers, sliding-window compute:
// each thread = one column x 16 consecutive output rows, 16 register accumulators.

#define BLOCK 256
#define TILE 70        // 64 + 2*3 halo
#define LDSW 72        // padded LDS row stride (bank spread)

__global__ __launch_bounds__(BLOCK, 2) void dwconv7_sym_kernel(
    const float* __restrict__ x, const float* __restrict__ w,
    float* __restrict__ out, int C)
{
    __shared__ float tile[TILE * LDSW];
    __shared__ float wsym[49];

    const int plane = blockIdx.x;       // n*C + c
    const int c = plane % C;
    const int tid = threadIdx.x;

    // --- Symmetrize weights: w_sym[i][j] = mean over 4 rotations ---
    // rot90^1: A[j][6-i], rot90^2: A[6-i][6-j], rot90^3: A[6-j][i]
    if (tid < 49) {
        const int i = tid / 7;
        const int j = tid - i * 7;
        const float* wc = w + c * 49;
        wsym[tid] = 0.25f * (wc[i * 7 + j]
                           + wc[j * 7 + (6 - i)]
                           + wc[(6 - i) * 7 + (6 - j)]
                           + wc[(6 - j) * 7 + i]);
    }

    // --- Stage 70x70 zero-padded plane into LDS ---
    const float* __restrict__ xp = x + (size_t)plane * 4096;
    for (int idx = tid; idx < TILE * TILE; idx += BLOCK) {
        const int ty = idx / TILE;
        const int tx = idx - ty * TILE;
        const int gy = ty - 3, gx = tx - 3;
        float v = 0.0f;
        if ((unsigned)gy < 64u && (unsigned)gx < 64u)
            v = xp[gy * 64 + gx];
        tile[ty * LDSW + tx] = v;
    }
    __syncthreads();

    // --- Weights LDS -> registers (block-uniform broadcast reads) ---
    float wreg[49];
    #pragma unroll
    for (int k = 0; k < 49; ++k) wreg[k] = wsym[k];

    // --- Sliding-window compute: thread -> (column ox, row strip oy0..oy0+15) ---
    const int ox  = tid & 63;           // wave = one full row of 64 columns
    const int oy0 = (tid >> 6) * 16;    // 4 strips of 16 rows

    float acc[16];
    #pragma unroll
    for (int t = 0; t < 16; ++t) acc[t] = 0.0f;

    // Tile rows needed for outputs oy0..oy0+15: tile rows oy0 .. oy0+21
    #pragma unroll
    for (int yl = 0; yl < 22; ++yl) {
        float r[7];
        const float* trow = &tile[(oy0 + yl) * LDSW + ox];
        #pragma unroll
        for (int j = 0; j < 7; ++j) r[j] = trow[j];
        // tile row (oy0+yl) feeds local outputs t with t <= yl <= t+6
        #pragma unroll
        for (int t = 0; t < 16; ++t) {
            if (t <= yl && yl <= t + 6) {   // folds to constant after unroll
                const int i = yl - t;       // kernel row 0..6
                #pragma unroll
                for (int j = 0; j < 7; ++j)
                    acc[t] += r[j] * wreg[i * 7 + j];
            }
        }
    }

    // --- Store: per t, wave writes 64 consecutive floats (coalesced) ---
    float* __restrict__ op = out + (size_t)plane * 4096 + ox;
    #pragma unroll
    for (int t = 0; t < 16; ++t)
        op[(oy0 + t) * 64] = acc[t];
}

extern "C" void kernel_launch(void* const* d_in, const int* in_sizes, int n_in,
                              void* d_out, int out_size, void* d_ws, size_t ws_size,
                              hipStream_t stream) {
    const float* x = (const float*)d_in[0];
    const float* w = (const float*)d_in[1];
    float* out = (float*)d_out;

    const int planes = in_sizes[0] / 4096;   // N*C = 6144
    const int C = in_sizes[1] / 49;          // 384

    dwconv7_sym_kernel<<<dim3(planes), dim3(BLOCK), 0, stream>>>(x, w, out, C);
}

// Round 2
// 245.879 us; speedup vs baseline: 1.0363x; 1.0363x over previous
//
#include <hip/hip_runtime.h>
#include <cstddef>

// Depthwise 7x7 conv, stride 1, pad 3, 4-fold rotational kernel symmetrization.
// x: [16,384,64,64] fp32, w: [384,1,7,7] fp32, out: [16,384,64,64] fp32.
//
// One block per (n,c) plane. Padded plane in LDS: tile col t <-> plane col t-4
// (interior at cols 4..67, 16B-aligned), tile row r <-> plane row r-3.
// Thread = 4x4 output patch: 3x ds_read_b128 per tile row, 784 FMA, float4 stores.
// Symmetrized 7x7 kernel has 13 unique values (C4 orbits) -> 13 weight VGPRs.

#define BLOCK 256
#define TROWS 70       // 64 + 2*3 halo rows
#define LDSW  72       // padded LDS row stride in floats (72*4 B, 16B-aligned rows)
#define NT4   (TROWS * LDSW / 4)   // 1260 float4 slots

// --- compile-time C4 orbit table for the symmetrized 7x7 kernel ---
constexpr int canon_of(int k) {
    const int i = k / 7, j = k % 7;
    const int a = i * 7 + j;
    const int b = j * 7 + (6 - i);
    const int c = (6 - i) * 7 + (6 - j);
    const int d = (6 - j) * 7 + i;
    int m = a;
    if (b < m) m = b;
    if (c < m) m = c;
    if (d < m) m = d;
    return m;
}
struct Tab { int cidx[49]; };
constexpr Tab build_tab() {
    Tab t{};
    int u = 0;
    for (int k = 0; k < 49; ++k)
        if (canon_of(k) == k) { t.cidx[k] = u; ++u; }
    for (int k = 0; k < 49; ++k) t.cidx[k] = t.cidx[canon_of(k)];
    return t;
}
constexpr Tab TAB = build_tab();   // 13 unique entries

__global__ __launch_bounds__(BLOCK, 4) void dwconv7_sym_kernel(
    const float* __restrict__ x, const float* __restrict__ w,
    float* __restrict__ out, int C)
{
    __shared__ __align__(16) float tile[TROWS * LDSW];
    __shared__ float wsym[49];
    float4* const tile4 = (float4*)tile;

    const int plane = blockIdx.x;       // n*C + c
    const int c = plane % C;
    const int tid = threadIdx.x;

    // --- issue global loads early: 4 float4 per thread, coalesced ---
    const float4* __restrict__ xp4 = (const float4*)(x + (size_t)plane * 4096);
    float4 gv[4];
    #pragma unroll
    for (int k = 0; k < 4; ++k)
        gv[k] = xp4[tid + 256 * k];

    // --- symmetrize weights (orbit-sum makes wsym C4-invariant) ---
    if (tid < 49) {
        const int i = tid / 7;
        const int j = tid - i * 7;
        const float* wc = w + c * 49;
        wsym[tid] = 0.25f * (wc[i * 7 + j]
                           + wc[j * 7 + (6 - i)]
                           + wc[(6 - i) * 7 + (6 - j)]
                           + wc[(6 - j) * 7 + i]);
    }

    // --- zero whole tile (covers halo), then barrier, then interior write ---
    const float4 z4 = make_float4(0.f, 0.f, 0.f, 0.f);
    #pragma unroll
    for (int k = 0; k < 5; ++k) {
        const int idx = tid + 256 * k;
        if (idx < NT4) tile4[idx] = z4;
    }
    __syncthreads();

    #pragma unroll
    for (int k = 0; k < 4; ++k) {
        const int g = tid + 256 * k;          // float4 index in plane
        const int row = g >> 4;               // 16 float4 per 64-wide row
        const int col4 = g & 15;
        tile4[(row + 3) * (LDSW / 4) + 1 + col4] = gv[k];
    }
    __syncthreads();

    // --- 13 unique weights -> registers (LDS broadcast reads, conflict-free) ---
    float wu[13];
    #pragma unroll
    for (int k = 0; k < 49; ++k)
        if (canon_of(k) == k) wu[TAB.cidx[k]] = wsym[k];

    // --- compute: thread -> cols x0..x0+3, rows y0..y0+3 ---
    const int cg = tid & 15;
    const int s  = tid >> 4;
    const int x0 = cg * 4;
    const int y0 = s * 4;

    float acc[4][4];
    #pragma unroll
    for (int t = 0; t < 4; ++t)
        #pragma unroll
        for (int d = 0; d < 4; ++d) acc[t][d] = 0.f;

    // out[y][xx] = sum_{i,j} tile[y+i][xx+j+1] * w[i][j]
    #pragma unroll
    for (int ro = 0; ro < 10; ++ro) {
        const float* base = &tile[(y0 + ro) * LDSW + x0];
        const float4 a = *(const float4*)(base);
        const float4 b = *(const float4*)(base + 4);
        const float4 cc = *(const float4*)(base + 8);
        const float r[12] = {a.x, a.y, a.z, a.w, b.x, b.y, b.z, b.w,
                             cc.x, cc.y, cc.z, cc.w};
        #pragma unroll
        for (int t = 0; t < 4; ++t) {
            if (ro >= t && ro <= t + 6) {     // compile-time after unroll
                const int i = ro - t;         // kernel row
                #pragma unroll
                for (int d = 0; d < 4; ++d)
                    #pragma unroll
                    for (int j = 0; j < 7; ++j)
                        acc[t][d] += r[1 + d + j] * wu[TAB.cidx[i * 7 + j]];
            }
        }
    }

    // --- store: float4 per output row, 16B-aligned, coalesced in 256B runs ---
    float* __restrict__ op = out + (size_t)plane * 4096;
    #pragma unroll
    for (int t = 0; t < 4; ++t) {
        float4 v;
        v.x = acc[t][0]; v.y = acc[t][1]; v.z = acc[t][2]; v.w = acc[t][3];
        *(float4*)&op[(y0 + t) * 64 + x0] = v;
    }
}

extern "C" void kernel_launch(void* const* d_in, const int* in_sizes, int n_in,
                              void* d_out, int out_size, void* d_ws, size_t ws_size,
                              hipStream_t stream) {
    const float* x = (const float*)d_in[0];
    const float* w = (const float*)d_in[1];
    float* out = (float*)d_out;

    const int planes = in_sizes[0] / 4096;   // N*C = 6144
    const int C = in_sizes[1] / 49;          // 384

    dwconv7_sym_kernel<<<dim3(planes), dim3(BLOCK), 0, stream>>>(x, w, out, C);
}

// Round 4
// 182.193 us; speedup vs baseline: 1.3985x; 1.3496x over previous
//
#include <hip/hip_runtime.h>
#include <cstddef>

// Depthwise 7x7 conv, stride 1, pad 3, 4-fold rotational kernel symmetrization.
// x: [16,384,64,64] fp32, w: [384,1,7,7] fp32, out: [16,384,64,64] fp32.
//
// Block = 128 threads, one (n,c) plane per block.
// LDS tile: contiguous 64-float rows (70 rows: 3 zero-halo top/bottom), 4-float
// guard pads front/back so edge-lane float4 reads stay in-bounds. All global
// loads AND stores are wave-contiguous 1024B runs; the output goes through an
// LDS transpose to achieve that on the store side.
// Thread = 4 cols x 8 consecutive rows: 42 ds_read_b128, 1568 FMA, 13 weights.

#define BLOCK 128
#define TROWS 70                      // 64 + 2*3 halo rows
#define TILE_F (4 + TROWS * 64 + 4)   // 4488 floats (front/back 4-float guards)

// --- compile-time C4 orbit table for the symmetrized 7x7 kernel (13 orbits) ---
constexpr int canon_of(int k) {
    const int i = k / 7, j = k % 7;
    const int a = i * 7 + j;
    const int b = j * 7 + (6 - i);
    const int c = (6 - i) * 7 + (6 - j);
    const int d = (6 - j) * 7 + i;
    int m = a;
    if (b < m) m = b;
    if (c < m) m = c;
    if (d < m) m = d;
    return m;
}
struct Tab { int cidx[49]; };
constexpr Tab build_tab() {
    Tab t{};
    int u = 0;
    for (int k = 0; k < 49; ++k)
        if (canon_of(k) == k) { t.cidx[k] = u; ++u; }
    for (int k = 0; k < 49; ++k) t.cidx[k] = t.cidx[canon_of(k)];
    return t;
}
constexpr Tab TAB = build_tab();

__global__ __launch_bounds__(BLOCK, 4) void dwconv7_sym_kernel(
    const float* __restrict__ x, const float* __restrict__ w,
    float* __restrict__ out, int C)
{
    __shared__ __align__(16) float tile[TILE_F];
    __shared__ float wsym[49];
    float4* const tile4 = (float4*)tile;     // 1122 float4 slots

    const int plane = blockIdx.x;            // n*C + c
    const int c = plane % C;
    const int tid = threadIdx.x;

    // --- issue global loads early: 8 float4 per thread, contiguous wave runs ---
    const float4* __restrict__ xp4 = (const float4*)(x + (size_t)plane * 4096);
    float4 gv[8];
    #pragma unroll
    for (int k = 0; k < 8; ++k)
        gv[k] = xp4[k * BLOCK + tid];        // 1024 float4 = whole plane

    // --- zero halo: front guard(4 floats)+3 rows = floats [0,196) = f4 [0,49);
    //     back 3 rows+guard = floats [4292,4488) = f4 [1073,1122) ---
    if (tid < 49) tile4[tid] = make_float4(0.f, 0.f, 0.f, 0.f);
    if (tid >= 64 && tid < 113) tile4[1073 + (tid - 64)] = make_float4(0.f, 0.f, 0.f, 0.f);

    // --- symmetrize weights ---
    if (tid < 49) {
        const int i = tid / 7;
        const int j = tid - i * 7;
        const float* wc = w + c * 49;
        wsym[tid] = 0.25f * (wc[i * 7 + j]
                           + wc[j * 7 + (6 - i)]
                           + wc[(6 - i) * 7 + (6 - j)]
                           + wc[(6 - j) * 7 + i]);
    }

    // --- interior: plane float4 g lands at tile4[49+g] (rows 3..66) ---
    #pragma unroll
    for (int k = 0; k < 8; ++k)
        tile4[49 + k * BLOCK + tid] = gv[k];
    __syncthreads();

    // --- 13 unique weights -> registers (broadcast reads) ---
    float wu[13];
    #pragma unroll
    for (int k = 0; k < 49; ++k)
        if (canon_of(k) == k) wu[TAB.cidx[k]] = wsym[k];

    // --- compute: thread = cols 4cg..4cg+3, out rows 8S..8S+7 ---
    const int cg = tid & 15;
    const int S  = tid >> 4;
    const int x0 = 4 * cg;
    // out[y][x0+d] = sum_{i,j} tile_row(y+i) col(x0+d+j-3) * w[i][j]
    // float addr = 4 + (y+i)*64 + x0+d+j-3 = (y+i)*64 + x0 + (d+j+1)

    float acc[8][4];
    #pragma unroll
    for (int t = 0; t < 8; ++t)
        #pragma unroll
        for (int d = 0; d < 4; ++d) acc[t][d] = 0.f;

    #pragma unroll
    for (int ro = 0; ro < 14; ++ro) {
        const int row = 8 * S + ro;
        const float4* p4 = (const float4*)(tile + row * 64 + x0);
        float4 a = p4[0], b = p4[1], cc = p4[2];   // plane cols x0-4 .. x0+7
        if (cg == 0)  { a.x = 0.f; a.y = 0.f; a.z = 0.f; a.w = 0.f; }  // cols <0
        if (cg == 15) { cc.x = 0.f; cc.y = 0.f; cc.z = 0.f; }          // cols >=64
        const float r[12] = {a.x, a.y, a.z, a.w, b.x, b.y, b.z, b.w,
                             cc.x, cc.y, cc.z, cc.w};
        #pragma unroll
        for (int t = 0; t < 8; ++t) {
            if (t <= ro && ro <= t + 6) {          // constant after unroll
                const int i = ro - t;              // kernel row
                #pragma unroll
                for (int d = 0; d < 4; ++d)
                    #pragma unroll
                    for (int j = 0; j < 7; ++j)
                        acc[t][d] += r[d + j + 1] * wu[TAB.cidx[i * 7 + j]];
            }
        }
    }

    // --- LDS transpose of output (reuse tile region), then contiguous stores ---
    __syncthreads();   // all tile reads done before overwrite
    #pragma unroll
    for (int t = 0; t < 8; ++t) {
        float4 v;
        v.x = acc[t][0]; v.y = acc[t][1]; v.z = acc[t][2]; v.w = acc[t][3];
        tile4[(8 * S + t) * 16 + cg] = v;          // plane image: f4 idx = row*16+cg
    }
    __syncthreads();

    float4* __restrict__ op4 = (float4*)(out + (size_t)plane * 4096);
    #pragma unroll
    for (int k = 0; k < 8; ++k) {
        const int g = k * BLOCK + tid;             // wave instr: 1024B contiguous
        op4[g] = tile4[g];
    }
}

extern "C" void kernel_launch(void* const* d_in, const int* in_sizes, int n_in,
                              void* d_out, int out_size, void* d_ws, size_t ws_size,
                              hipStream_t stream) {
    const float* x = (const float*)d_in[0];
    const float* w = (const float*)d_in[1];
    float* out = (float*)d_out;

    const int planes = in_sizes[0] / 4096;   // N*C = 6144
    const int C = in_sizes[1] / 49;          // 384

    dwconv7_sym_kernel<<<dim3(planes), dim3(BLOCK), 0, stream>>>(x, w, out, C);
}